// Round 4
// baseline (427.024 us; speedup 1.0000x reference)
//
#include <hip/hip_runtime.h>
#include <stdint.h>

#define BLOCK 256
#define ITEMS 8
#define TILE (BLOCK * ITEMS)   // 2048 elements per block
#define WPB (TILE / 64)        // 32 bitmask words per block
#define MAXSEG 64
#define THRESH 0.1f

typedef unsigned long long u64;

__device__ __forceinline__ int find_seg(const int* rs, int n_seg, int i) {
    // largest s with rs[s] <= i
    int lo = 0, hi = n_seg;
    while (hi - lo > 1) {
        int mid = (lo + hi) >> 1;
        if (rs[mid] <= i) lo = mid; else hi = mid;
    }
    return lo;
}

// Pass 1 (fused): single read of score producing
//   - threshold keep-bitmask (s > THRESH)  [min-tied bits fixed up in k_mid]
//   - per-block keep counts (threshold-only; fixed up in k_mid)
//   - per-block packed (min_bits<<32 | idx) partials, <=2 segments per block
__global__ __launch_bounds__(BLOCK) void k_pass1(const float* __restrict__ score,
        const int* __restrict__ row_splits, int n_seg, int n, int nwords,
        u64* __restrict__ partial_val, int* __restrict__ partial_seg,
        u64* __restrict__ bitmask, int* __restrict__ block_counts) {
    __shared__ int rs[MAXSEG + 1];
    __shared__ u64 wval[8];
    __shared__ int wseg[8];
    __shared__ int wsum[4];
    for (int j = threadIdx.x; j <= n_seg; j += BLOCK) rs[j] = row_splits[j];
    __syncthreads();
    int lane = threadIdx.x & 63, wv = threadIdx.x >> 6;
    int wbase = blockIdx.x * TILE + wv * 512;
    u64 m0 = ~0ull, m1 = ~0ull, myword = 0;
    int sf = -1, sl = -1, cnt = 0;
    if (wbase < n) {   // wave-uniform
        int wend = min(n, wbase + 512) - 1;
        sf = find_seg(rs, n_seg, wbase);
        sl = find_seg(rs, n_seg, wend);
        int bval = (sl != sf) ? rs[sf + 1] : 0x7FFFFFFF;
        #pragma unroll
        for (int it = 0; it < 8; it++) {
            int i = wbase + it * 64 + lane;
            bool keep = false;
            if (i < n) {
                float v = score[i];
                u64 p = ((u64)__float_as_uint(v) << 32) | (unsigned int)i;
                if (i < bval) m0 = min(m0, p); else m1 = min(m1, p);
                keep = v > THRESH;
            }
            u64 bal = __ballot(keep);
            if (lane == it) myword = bal;
            cnt += __popcll(bal);
        }
        for (int o = 32; o > 0; o >>= 1) {
            m0 = min(m0, (u64)__shfl_down((unsigned long long)m0, o, 64));
            m1 = min(m1, (u64)__shfl_down((unsigned long long)m1, o, 64));
        }
        if (lane < 8) {
            int w = (wbase >> 6) + lane;
            if (w < nwords) bitmask[w] = myword;
        }
    }
    if (lane == 0) {
        wval[2 * wv] = m0;     wseg[2 * wv] = sf;
        wval[2 * wv + 1] = m1; wseg[2 * wv + 1] = (sl != sf) ? sl : -1;
        wsum[wv] = cnt;        // cnt==0 for inactive waves
    }
    __syncthreads();
    if (threadIdx.x == 0) {
        int base = blockIdx.x * TILE;
        int endi = min(n, base + TILE) - 1;
        int s0 = find_seg(rs, n_seg, base);
        int s1 = find_seg(rs, n_seg, endi);
        u64 o0 = ~0ull, o1 = ~0ull;
        for (int k = 0; k < 8; k++) {
            if (wseg[k] == s0) o0 = min(o0, wval[k]);
            else if (wseg[k] == s1) o1 = min(o1, wval[k]);
        }
        partial_val[2 * blockIdx.x] = o0;
        partial_seg[2 * blockIdx.x] = s0;
        partial_val[2 * blockIdx.x + 1] = o1;
        partial_seg[2 * blockIdx.x + 1] = (s1 != s0) ? s1 : -1;
        block_counts[blockIdx.x] = wsum[0] + wsum[1] + wsum[2] + wsum[3];
    }
}

// Pass 2 (single block): segment-min reduce -> min-tie bit fixup -> block-count
// scan -> newrs/rep_pos queries. Everything it touches is tiny / L2-warm.
__global__ __launch_bounds__(BLOCK) void k_mid(const float* __restrict__ score,
        const int* __restrict__ row_splits, int n_seg, int n, int nb, int M,
        const u64* __restrict__ partial_val, const int* __restrict__ partial_seg,
        u64* __restrict__ bitmask, int* __restrict__ block_counts,
        int* __restrict__ block_offsets,
        int* __restrict__ rep_pos, int* __restrict__ newrs_out) {
    __shared__ int rs[MAXSEG + 1];
    __shared__ u64 segp[MAXSEG];
    __shared__ int wtot[4];
    for (int j = threadIdx.x; j <= n_seg; j += BLOCK) rs[j] = row_splits[j];
    __syncthreads();
    int lane = threadIdx.x & 63, wv = threadIdx.x >> 6;

    // Phase 1: per-segment packed min from block partials (one wave per segment)
    for (int s = wv; s < n_seg; s += 4) {
        int lo = rs[s], hi = rs[s + 1];
        u64 m = ~0ull;
        if (hi > lo) {
            int e0 = 2 * (lo / TILE), e1 = 2 * ((hi - 1) / TILE) + 1;
            for (int e = e0 + lane; e <= e1; e += 64)
                if (partial_seg[e] == s) m = min(m, partial_val[e]);
        }
        for (int o = 32; o > 0; o >>= 1)
            m = min(m, (u64)__shfl_down((unsigned long long)m, o, 64));
        if (lane == 0) segp[s] = m;
    }
    __syncthreads();

    // Phase 2: fixup — set keep bits for elements tied with a segmin <= THRESH
    for (int s = wv; s < n_seg; s += 4) {
        u64 sp = segp[s];
        if (sp == ~0ull) continue;
        unsigned int smb = (unsigned int)(sp >> 32);
        if (__uint_as_float(smb) > THRESH) continue;   // threshold bits already cover
        int lo = rs[s], hi = rs[s + 1];
        int e0 = 2 * (lo / TILE), e1 = 2 * ((hi - 1) / TILE) + 1;
        for (int eb = e0; eb <= e1; eb += 64) {
            int e = eb + lane;
            bool match = (e <= e1) && (partial_seg[e] == s) &&
                         ((unsigned int)(partial_val[e] >> 32) == smb);
            u64 mask = __ballot(match);
            while (mask) {
                int j = __ffsll((unsigned long long)mask) - 1;
                mask &= mask - 1;
                int b = (eb + j) >> 1;
                int rlo = max(b * TILE, lo);
                int rhi = min(min((b + 1) * TILE, n), hi);
                int newc = 0;
                for (int i = rlo + lane; i < rhi; i += 64) {
                    if (__float_as_uint(score[i]) == smb) {
                        atomicOr(&bitmask[i >> 6], 1ull << (i & 63));
                        newc++;
                    }
                }
                for (int o = 32; o > 0; o >>= 1) newc += __shfl_down(newc, o, 64);
                if (lane == 0 && newc) atomicAdd(&block_counts[b], newc);
            }
        }
    }
    __syncthreads();

    // Phase 3: exclusive scan of block_counts -> block_offsets
    {
        int per = (nb + BLOCK - 1) / BLOCK;
        int s0 = per * threadIdx.x, e0 = min(nb, s0 + per);
        int sum = 0;
        for (int i = s0; i < e0; i++) sum += block_counts[i];
        int incl = sum;
        for (int o = 1; o < 64; o <<= 1) {
            int t = __shfl_up(incl, o, 64);
            if (lane >= o) incl += t;
        }
        if (lane == 63) wtot[wv] = incl;
        __syncthreads();
        int excl = incl - sum;
        for (int k = 0; k < wv; k++) excl += wtot[k];
        for (int i = s0; i < e0; i++) { block_offsets[i] = excl; excl += block_counts[i]; }
    }
    __syncthreads();

    // Phase 4: queries — newrs[0..n_seg] and rep_pos[0..n_seg-1] (one wave/query)
    int nq = 2 * n_seg + 1;
    for (int q = wv; q < nq; q += 4) {
        unsigned int uidx;
        if (q <= n_seg) uidx = (unsigned int)rs[q];
        else uidx = (unsigned int)(segp[q - (n_seg + 1)] & 0xFFFFFFFFu);
        int result;
        if (uidx >= (unsigned int)n) {
            result = M;
        } else {
            int idx = (int)uidx;
            int b = idx / TILE;
            int wq = idx >> 6;
            int cnt = 0;
            for (int w = b * WPB + lane; w < wq; w += 64) cnt += __popcll(bitmask[w]);
            if (lane == 0 && (idx & 63))
                cnt += __popcll(bitmask[wq] & ((1ull << (idx & 63)) - 1));
            for (int o = 32; o > 0; o >>= 1) cnt += __shfl_down(cnt, o, 64);
            result = block_offsets[b] + cnt;
        }
        if (lane == 0) {
            if (q <= n_seg) newrs_out[q] = result;
            else rep_pos[q - (n_seg + 1)] = result;
        }
    }
}

// Pass 3: outputs from bitmask only (no score re-read).
__global__ __launch_bounds__(BLOCK) void k_output(const int* __restrict__ row_splits,
        int n_seg, int n,
        const int* __restrict__ rep_pos, const u64* __restrict__ bitmask,
        const int* __restrict__ block_offsets,
        int* __restrict__ sel_out, int* __restrict__ back_out) {
    __shared__ int rs[MAXSEG + 1];
    __shared__ int srep[MAXSEG];
    __shared__ u64 swords[WPB];
    __shared__ int wpre[WPB];
    for (int j = threadIdx.x; j <= n_seg; j += BLOCK) rs[j] = row_splits[j];
    for (int j = threadIdx.x; j < n_seg; j += BLOCK) srep[j] = rep_pos[j];
    int base = blockIdx.x * TILE;
    int nw = min(WPB, (n - base + 63) >> 6);
    for (int j = threadIdx.x; j < nw; j += BLOCK) swords[j] = bitmask[(base >> 6) + j];
    __syncthreads();
    if (threadIdx.x == 0) {
        int acc = 0;
        for (int k = 0; k < nw; k++) { wpre[k] = acc; acc += __popcll(swords[k]); }
    }
    __syncthreads();
    int bo = block_offsets[blockIdx.x];
    int lane = threadIdx.x & 63, wv = threadIdx.x >> 6;
    #pragma unroll
    for (int it = 0; it < 8; it++) {
        int widx = wv * 8 + it;
        int i = base + widx * 64 + lane;
        if (i < n) {
            u64 word = swords[widx];
            bool keep = (word >> lane) & 1;
            int val;
            if (keep) {
                int pos = bo + wpre[widx] + __popcll(word & ((1ull << lane) - 1));
                val = pos;
                sel_out[pos] = i;
            } else {
                int seg = find_seg(rs, n_seg, i);
                val = srep[seg];
            }
            back_out[i] = val;
        }
    }
}

extern "C" void kernel_launch(void* const* d_in, const int* in_sizes, int n_in,
                              void* d_out, int out_size, void* d_ws, size_t ws_size,
                              hipStream_t stream) {
    const float* score = (const float*)d_in[0];
    const int* row_splits = (const int*)d_in[1];
    int n = in_sizes[0];
    int n_seg = in_sizes[1] - 1;
    int M = out_size - (n_seg + 1) - n;
    int nb = (n + TILE - 1) / TILE;
    int nwords = (n + 63) / 64;

    u64* partial_val  = (u64*)d_ws;                      // 2*nb u64
    int* partial_seg  = (int*)(partial_val + 2 * nb);    // 2*nb int
    int* rep_pos      = partial_seg + 2 * nb;            // 64 int
    int* block_counts = rep_pos + 64;                    // nb int
    int* block_offsets= block_counts + nb;               // nb int
    uintptr_t bm_addr = (uintptr_t)(block_offsets + nb);
    bm_addr = (bm_addr + 7) & ~(uintptr_t)7;
    u64* bitmask      = (u64*)bm_addr;                   // nwords u64

    int* out = (int*)d_out;
    int* sel_out   = out;
    int* newrs_out = out + M;
    int* back_out  = out + M + (n_seg + 1);

    hipLaunchKernelGGL(k_pass1, dim3(nb), dim3(BLOCK), 0, stream,
                       score, row_splits, n_seg, n, nwords,
                       partial_val, partial_seg, bitmask, block_counts);
    hipLaunchKernelGGL(k_mid, dim3(1), dim3(BLOCK), 0, stream,
                       score, row_splits, n_seg, n, nb, M,
                       partial_val, partial_seg, bitmask, block_counts,
                       block_offsets, rep_pos, newrs_out);
    hipLaunchKernelGGL(k_output, dim3(nb), dim3(BLOCK), 0, stream,
                       row_splits, n_seg, n, rep_pos, bitmask,
                       block_offsets, sel_out, back_out);
}

// Round 5
// 186.885 us; speedup vs baseline: 2.2850x; 2.2850x over previous
//
#include <hip/hip_runtime.h>
#include <stdint.h>

#define BLOCK 256
#define ITEMS 8
#define TILE (BLOCK * ITEMS)   // 2048 elements per block
#define WPB (TILE / 64)        // 32 bitmask words per block
#define MAXSEG 64
#define THRESH 0.1f

typedef unsigned long long u64;

__device__ __forceinline__ int find_seg(const int* rs, int n_seg, int i) {
    // largest s with rs[s] <= i
    int lo = 0, hi = n_seg;
    while (hi - lo > 1) {
        int mid = (lo + hi) >> 1;
        if (rs[mid] <= i) lo = mid; else hi = mid;
    }
    return lo;
}

// Pass 1 (fused): single read of score producing
//   - threshold keep-bitmask (s > THRESH)  [min-tied bits fixed up in k_segfix]
//   - per-block keep counts (threshold-only; fixed up in k_segfix)
//   - per-block packed (min_bits<<32 | idx) partials, <=2 segments per block
__global__ __launch_bounds__(BLOCK) void k_pass1(const float* __restrict__ score,
        const int* __restrict__ row_splits, int n_seg, int n, int nwords,
        u64* __restrict__ partial_val, int* __restrict__ partial_seg,
        u64* __restrict__ bitmask, int* __restrict__ block_counts) {
    __shared__ int rs[MAXSEG + 1];
    __shared__ u64 wval[8];
    __shared__ int wseg[8];
    __shared__ int wsum[4];
    for (int j = threadIdx.x; j <= n_seg; j += BLOCK) rs[j] = row_splits[j];
    __syncthreads();
    int lane = threadIdx.x & 63, wv = threadIdx.x >> 6;
    int wbase = blockIdx.x * TILE + wv * 512;
    u64 m0 = ~0ull, m1 = ~0ull, myword = 0;
    int sf = -1, sl = -1, cnt = 0;
    if (wbase < n) {   // wave-uniform
        int wend = min(n, wbase + 512) - 1;
        sf = find_seg(rs, n_seg, wbase);
        sl = find_seg(rs, n_seg, wend);
        int bval = (sl != sf) ? rs[sf + 1] : 0x7FFFFFFF;
        #pragma unroll
        for (int it = 0; it < 8; it++) {
            int i = wbase + it * 64 + lane;
            bool keep = false;
            if (i < n) {
                float v = score[i];
                u64 p = ((u64)__float_as_uint(v) << 32) | (unsigned int)i;
                if (i < bval) m0 = min(m0, p); else m1 = min(m1, p);
                keep = v > THRESH;
            }
            u64 bal = __ballot(keep);
            if (lane == it) myword = bal;
            cnt += __popcll(bal);
        }
        for (int o = 32; o > 0; o >>= 1) {
            m0 = min(m0, (u64)__shfl_down((unsigned long long)m0, o, 64));
            m1 = min(m1, (u64)__shfl_down((unsigned long long)m1, o, 64));
        }
        if (lane < 8) {
            int w = (wbase >> 6) + lane;
            if (w < nwords) bitmask[w] = myword;
        }
    }
    if (lane == 0) {
        wval[2 * wv] = m0;     wseg[2 * wv] = sf;
        wval[2 * wv + 1] = m1; wseg[2 * wv + 1] = (sl != sf) ? sl : -1;
        wsum[wv] = cnt;
    }
    __syncthreads();
    if (threadIdx.x == 0) {
        int base = blockIdx.x * TILE;
        int endi = min(n, base + TILE) - 1;
        int s0 = find_seg(rs, n_seg, base);
        int s1 = find_seg(rs, n_seg, endi);
        u64 o0 = ~0ull, o1 = ~0ull;
        for (int k = 0; k < 8; k++) {
            if (wseg[k] == s0) o0 = min(o0, wval[k]);
            else if (wseg[k] == s1) o1 = min(o1, wval[k]);
        }
        partial_val[2 * blockIdx.x] = o0;
        partial_seg[2 * blockIdx.x] = s0;
        partial_val[2 * blockIdx.x + 1] = o1;
        partial_seg[2 * blockIdx.x + 1] = (s1 != s0) ? s1 : -1;
        block_counts[blockIdx.x] = wsum[0] + wsum[1] + wsum[2] + wsum[3];
    }
}

// Pass 2: one block PER SEGMENT (parallel, latency-hidden across 64 blocks):
// reduce block partials -> seg_packed[s]; if segmin <= THRESH, set keep bits
// for min-tied elements (re-reads only the matched ~2048-elem tiles).
__global__ __launch_bounds__(BLOCK) void k_segfix(const float* __restrict__ score,
        const int* __restrict__ row_splits, int n_seg, int n,
        const u64* __restrict__ partial_val, const int* __restrict__ partial_seg,
        u64* __restrict__ seg_packed, u64* __restrict__ bitmask,
        int* __restrict__ block_counts) {
    __shared__ u64 wred[4];
    __shared__ int nmatch;
    __shared__ int mlist[64];
    int s = blockIdx.x;
    int lo = row_splits[s], hi = row_splits[s + 1];
    int lane = threadIdx.x & 63, wv = threadIdx.x >> 6;
    if (threadIdx.x == 0) nmatch = 0;
    u64 m = ~0ull;
    int e0 = 0, e1 = -1;
    if (hi > lo) {
        e0 = 2 * (lo / TILE);
        e1 = 2 * ((hi - 1) / TILE) + 1;
        for (int e = e0 + threadIdx.x; e <= e1; e += BLOCK)
            if (partial_seg[e] == s) m = min(m, partial_val[e]);
    }
    for (int o = 32; o > 0; o >>= 1)
        m = min(m, (u64)__shfl_down((unsigned long long)m, o, 64));
    if (lane == 0) wred[wv] = m;
    __syncthreads();
    if (threadIdx.x == 0) {
        u64 r = min(min(wred[0], wred[1]), min(wred[2], wred[3]));
        wred[0] = r;
        seg_packed[s] = r;
    }
    __syncthreads();
    u64 sp = wred[0];
    if (sp == ~0ull) return;
    unsigned int smb = (unsigned int)(sp >> 32);
    if (__uint_as_float(smb) > THRESH) return;   // threshold bit already covers min elems
    // collect blocks containing min-valued elements
    for (int e = e0 + threadIdx.x; e <= e1; e += BLOCK) {
        if (partial_seg[e] == s && (unsigned int)(partial_val[e] >> 32) == smb) {
            int k = atomicAdd(&nmatch, 1);   // LDS atomic, rare
            if (k < 64) mlist[k] = e >> 1;
        }
    }
    __syncthreads();
    int nm = min(nmatch, 64);
    for (int k = 0; k < nm; k++) {
        int b = mlist[k];
        int rlo = max(b * TILE, lo);
        int rhi = min(min((b + 1) * TILE, n), hi);
        int c = 0;
        for (int i = rlo + threadIdx.x; i < rhi; i += BLOCK) {
            if (__float_as_uint(score[i]) == smb) {
                atomicOr(&bitmask[i >> 6], 1ull << (i & 63));
                c++;
            }
        }
        for (int o = 32; o > 0; o >>= 1) c += __shfl_down(c, o, 64);
        if (lane == 0 && c) atomicAdd(&block_counts[b], c);
    }
}

// Pass 3: single-block exclusive scan of nb block counts
__global__ __launch_bounds__(BLOCK) void k_scan(const int* __restrict__ counts,
                                                int* __restrict__ offsets, int nb) {
    __shared__ int wtot[BLOCK / 64];
    int per = (nb + BLOCK - 1) / BLOCK;
    int s = per * threadIdx.x, e = min(nb, s + per);
    int sum = 0;
    for (int i = s; i < e; i++) sum += counts[i];
    int lane = threadIdx.x & 63, wv = threadIdx.x >> 6;
    int incl = sum;
    for (int o = 1; o < 64; o <<= 1) {
        int t = __shfl_up(incl, o, 64);
        if (lane >= o) incl += t;
    }
    if (lane == 63) wtot[wv] = incl;
    __syncthreads();
    int excl = incl - sum;
    for (int k = 0; k < wv; k++) excl += wtot[k];
    for (int i = s; i < e; i++) { offsets[i] = excl; excl += counts[i]; }
}

// Pass 4: exclusive kept-count at query indices via bitmask popcount -> newrs + rep_pos
__global__ __launch_bounds__(BLOCK) void k_query(const int* __restrict__ row_splits,
        int n_seg, int n, int M,
        const u64* __restrict__ seg_packed, const u64* __restrict__ bitmask,
        const int* __restrict__ block_offsets,
        int* __restrict__ rep_pos, int* __restrict__ newrs_out) {
    int lane = threadIdx.x & 63, wv = threadIdx.x >> 6;
    int q = blockIdx.x * (BLOCK / 64) + wv;
    int nq = 2 * n_seg + 1;
    if (q >= nq) return;
    unsigned int uidx;
    if (q <= n_seg) uidx = (unsigned int)row_splits[q];
    else uidx = (unsigned int)(seg_packed[q - (n_seg + 1)] & 0xFFFFFFFFu);
    int result;
    if (uidx >= (unsigned int)n) {
        result = M;
    } else {
        int idx = (int)uidx;
        int b = idx / TILE;
        int wq = idx >> 6;
        int cnt = 0;
        for (int w = b * WPB + lane; w < wq; w += 64) cnt += __popcll(bitmask[w]);
        if (lane == 0 && (idx & 63))
            cnt += __popcll(bitmask[wq] & ((1ull << (idx & 63)) - 1));
        for (int o = 32; o > 0; o >>= 1) cnt += __shfl_down(cnt, o, 64);
        result = block_offsets[b] + cnt;
    }
    if (lane == 0) {
        if (q <= n_seg) newrs_out[q] = result;
        else rep_pos[q - (n_seg + 1)] = result;
    }
}

// Pass 5: outputs from bitmask only (no score re-read).
__global__ __launch_bounds__(BLOCK) void k_output(const int* __restrict__ row_splits,
        int n_seg, int n,
        const int* __restrict__ rep_pos, const u64* __restrict__ bitmask,
        const int* __restrict__ block_offsets,
        int* __restrict__ sel_out, int* __restrict__ back_out) {
    __shared__ int rs[MAXSEG + 1];
    __shared__ int srep[MAXSEG];
    __shared__ u64 swords[WPB];
    __shared__ int wpre[WPB];
    for (int j = threadIdx.x; j <= n_seg; j += BLOCK) rs[j] = row_splits[j];
    for (int j = threadIdx.x; j < n_seg; j += BLOCK) srep[j] = rep_pos[j];
    int base = blockIdx.x * TILE;
    int nw = min(WPB, (n - base + 63) >> 6);
    for (int j = threadIdx.x; j < nw; j += BLOCK) swords[j] = bitmask[(base >> 6) + j];
    __syncthreads();
    if (threadIdx.x == 0) {
        int acc = 0;
        for (int k = 0; k < nw; k++) { wpre[k] = acc; acc += __popcll(swords[k]); }
    }
    __syncthreads();
    int bo = block_offsets[blockIdx.x];
    int lane = threadIdx.x & 63, wv = threadIdx.x >> 6;
    #pragma unroll
    for (int it = 0; it < 8; it++) {
        int widx = wv * 8 + it;
        int i = base + widx * 64 + lane;
        if (i < n) {
            u64 word = swords[widx];
            bool keep = (word >> lane) & 1;
            int val;
            if (keep) {
                int pos = bo + wpre[widx] + __popcll(word & ((1ull << lane) - 1));
                val = pos;
                sel_out[pos] = i;
            } else {
                int seg = find_seg(rs, n_seg, i);
                val = srep[seg];
            }
            back_out[i] = val;
        }
    }
}

extern "C" void kernel_launch(void* const* d_in, const int* in_sizes, int n_in,
                              void* d_out, int out_size, void* d_ws, size_t ws_size,
                              hipStream_t stream) {
    const float* score = (const float*)d_in[0];
    const int* row_splits = (const int*)d_in[1];
    int n = in_sizes[0];
    int n_seg = in_sizes[1] - 1;
    int M = out_size - (n_seg + 1) - n;
    int nb = (n + TILE - 1) / TILE;
    int nwords = (n + 63) / 64;

    u64* seg_packed   = (u64*)d_ws;                      // 64 u64
    u64* partial_val  = seg_packed + MAXSEG;             // 2*nb u64
    int* partial_seg  = (int*)(partial_val + 2 * nb);    // 2*nb int
    int* rep_pos      = partial_seg + 2 * nb;            // 64 int
    int* block_counts = rep_pos + 64;                    // nb int
    int* block_offsets= block_counts + nb;               // nb int
    uintptr_t bm_addr = (uintptr_t)(block_offsets + nb);
    bm_addr = (bm_addr + 7) & ~(uintptr_t)7;
    u64* bitmask      = (u64*)bm_addr;                   // nwords u64

    int* out = (int*)d_out;
    int* sel_out   = out;
    int* newrs_out = out + M;
    int* back_out  = out + M + (n_seg + 1);

    hipLaunchKernelGGL(k_pass1, dim3(nb), dim3(BLOCK), 0, stream,
                       score, row_splits, n_seg, n, nwords,
                       partial_val, partial_seg, bitmask, block_counts);
    hipLaunchKernelGGL(k_segfix, dim3(n_seg), dim3(BLOCK), 0, stream,
                       score, row_splits, n_seg, n,
                       partial_val, partial_seg, seg_packed, bitmask, block_counts);
    hipLaunchKernelGGL(k_scan, dim3(1), dim3(BLOCK), 0, stream,
                       block_counts, block_offsets, nb);
    int nq = 2 * n_seg + 1;
    int qblocks = (nq + (BLOCK / 64) - 1) / (BLOCK / 64);
    hipLaunchKernelGGL(k_query, dim3(qblocks), dim3(BLOCK), 0, stream,
                       row_splits, n_seg, n, M, seg_packed, bitmask,
                       block_offsets, rep_pos, newrs_out);
    hipLaunchKernelGGL(k_output, dim3(nb), dim3(BLOCK), 0, stream,
                       row_splits, n_seg, n, rep_pos, bitmask,
                       block_offsets, sel_out, back_out);
}